// Round 1
// baseline (393.950 us; speedup 1.0000x reference)
//
#include <hip/hip_runtime.h>

// Problem constants (from reference): BATCH*SEQ = 16384 tokens, 128 experts,
// hidden 2880, top-k 4.
constexpr int T_TOK  = 16384;
constexpr int NEXP   = 128;
constexpr int HID    = 2880;
constexpr int TOPK   = 4;

constexpr int KSPLIT = 4;
constexpr int KS     = HID / KSPLIT;   // 720
constexpr int BM     = 128;            // token tile
constexpr int BK     = 48;             // k tile (720 = 15*48)
constexpr int NIT    = KS / BK;        // 15
constexpr int LSTR   = 52;             // padded LDS row stride (floats), 16B-aligned

// ---------------------------------------------------------------------------
// Kernel 1: partial GEMM. part[split][token][expert] = sum over K-range of
// x[token][k] * w[expert][k].  Grid: 128 token-tiles * 4 K-splits = 512 blocks.
// 256 threads, per-thread 8x8 register tile (rows/cols interleaved by 16 so
// LDS reads across a wave hit distinct banks; 16-lane broadcasts on x).
// ---------------------------------------------------------------------------
__global__ __launch_bounds__(256, 2)
void gemm_partial(const float* __restrict__ x, const float* __restrict__ w,
                  float* __restrict__ part) {
    const int tile  = blockIdx.x >> 2;   // 0..127
    const int split = blockIdx.x & 3;    // 0..3
    const int tid = threadIdx.x;
    const int tx = tid & 15;             // expert-column group
    const int ty = tid >> 4;             // token-row group

    __shared__ float xs[BM * LSTR];
    __shared__ float wsh[NEXP * LSTR];

    float acc[8][8];
#pragma unroll
    for (int i = 0; i < 8; ++i)
#pragma unroll
        for (int j = 0; j < 8; ++j) acc[i][j] = 0.f;

    const float* xbase = x + (size_t)tile * BM * HID + split * KS;
    const float* wbase = w + (size_t)split * KS;

    for (int it = 0; it < NIT; ++it) {
        const int k0 = it * BK;
        // stage x tile: 128 rows x 48 floats = 1536 float4, 6 per thread
#pragma unroll
        for (int r = 0; r < 6; ++r) {
            int f = tid + 256 * r;
            int row = f / 12;
            int c4  = f % 12;
            float4 v = *reinterpret_cast<const float4*>(
                xbase + (size_t)row * HID + k0 + c4 * 4);
            *reinterpret_cast<float4*>(&xs[row * LSTR + c4 * 4]) = v;
        }
        // stage w tile: 128 experts x 48 floats
#pragma unroll
        for (int r = 0; r < 6; ++r) {
            int f = tid + 256 * r;
            int row = f / 12;
            int c4  = f % 12;
            float4 v = *reinterpret_cast<const float4*>(
                wbase + (size_t)row * HID + k0 + c4 * 4);
            *reinterpret_cast<float4*>(&wsh[row * LSTR + c4 * 4]) = v;
        }
        __syncthreads();

#pragma unroll
        for (int kk = 0; kk < BK; kk += 4) {
            float4 xq[8], wq[8];
#pragma unroll
            for (int i = 0; i < 8; ++i)
                xq[i] = *reinterpret_cast<const float4*>(
                    &xs[(ty + 16 * i) * LSTR + kk]);
#pragma unroll
            for (int j = 0; j < 8; ++j)
                wq[j] = *reinterpret_cast<const float4*>(
                    &wsh[(tx + 16 * j) * LSTR + kk]);
#pragma unroll
            for (int i = 0; i < 8; ++i)
#pragma unroll
                for (int j = 0; j < 8; ++j) {
                    acc[i][j] = fmaf(xq[i].x, wq[j].x, acc[i][j]);
                    acc[i][j] = fmaf(xq[i].y, wq[j].y, acc[i][j]);
                    acc[i][j] = fmaf(xq[i].z, wq[j].z, acc[i][j]);
                    acc[i][j] = fmaf(xq[i].w, wq[j].w, acc[i][j]);
                }
        }
        __syncthreads();
    }

    // write partial tile: part[split][token][expert]
#pragma unroll
    for (int i = 0; i < 8; ++i) {
        const int t = tile * BM + ty + 16 * i;
        float* p = part + ((size_t)split * T_TOK + t) * NEXP;
#pragma unroll
        for (int j = 0; j < 8; ++j) p[tx + 16 * j] = acc[i][j];
    }
}

// ---------------------------------------------------------------------------
// Kernel 2: per-token reduce over K-splits + bias (+vision bias), top-4 with
// jax.lax.top_k tie-break (lower index first on equal values), softmax over
// the 4 selected logits, scatter into dense scores + write indices (as float).
// One wave (64 lanes) per token; lane l owns experts l and l+64.
// ---------------------------------------------------------------------------
__global__ __launch_bounds__(256)
void topk_scatter(const float* __restrict__ part, const int* __restrict__ mm,
                  const float* __restrict__ bias, const float* __restrict__ vbias,
                  float* __restrict__ out) {
    const int lane = threadIdx.x & 63;
    const int wid  = threadIdx.x >> 6;
    const int t    = blockIdx.x * 4 + wid;

    const int e0 = lane, e1 = 64 + lane;
    float v0 = bias[e0];
    float v1 = bias[e1];
    if (mm[t] != 0) { v0 += vbias[e0]; v1 += vbias[e1]; }
#pragma unroll
    for (int s = 0; s < KSPLIT; ++s) {
        const float* p = part + ((size_t)s * T_TOK + t) * NEXP;
        v0 += p[e0];
        v1 += p[e1];
    }

    float lv0 = v0, lv1 = v1;
    float tv[TOPK];
    int   ti[TOPK];
#pragma unroll
    for (int k = 0; k < TOPK; ++k) {
        float bv; int bi;
        if (lv0 >= lv1) { bv = lv0; bi = e0; }   // tie -> lower index (e0 < e1)
        else            { bv = lv1; bi = e1; }
#pragma unroll
        for (int off = 32; off >= 1; off >>= 1) {
            float ov = __shfl_xor(bv, off, 64);
            int   oi = __shfl_xor(bi, off, 64);
            if (ov > bv || (ov == bv && oi < bi)) { bv = ov; bi = oi; }
        }
        tv[k] = bv;
        ti[k] = bi;
        if (bi == e0) lv0 = -__builtin_inff();
        if (bi == e1) lv1 = -__builtin_inff();
    }

    // softmax over the 4 selected (tv[0] is the max; values descending)
    const float m = tv[0];
    float ex[TOPK], s = 0.f;
#pragma unroll
    for (int k = 0; k < TOPK; ++k) { ex[k] = expf(tv[k] - m); s += ex[k]; }
    const float inv = 1.0f / s;

    float s0 = 0.f, s1 = 0.f;
#pragma unroll
    for (int k = 0; k < TOPK; ++k) {
        const float p = ex[k] * inv;
        if (ti[k] == e0) s0 = p;
        if (ti[k] == e1) s1 = p;
    }
    out[(size_t)t * NEXP + e0] = s0;
    out[(size_t)t * NEXP + e1] = s1;
    if (lane < TOPK)
        out[(size_t)T_TOK * NEXP + (size_t)t * TOPK + lane] = (float)ti[lane];
}

extern "C" void kernel_launch(void* const* d_in, const int* in_sizes, int n_in,
                              void* d_out, int out_size, void* d_ws, size_t ws_size,
                              hipStream_t stream) {
    const float* x     = (const float*)d_in[0];   // (4,4096,2880) fp32
    const int*   mm    = (const int*)d_in[1];     // (4,4096) bool -> int32 per contract
    const float* w     = (const float*)d_in[2];   // (128,2880) fp32
    const float* bias  = (const float*)d_in[3];   // (128,)
    const float* vbias = (const float*)d_in[4];   // (128,)
    float* out = (float*)d_out;                   // [scores 16384*128 | idx 16384*4] fp32
    float* part = (float*)d_ws;                   // needs 4*16384*128*4 = 33.55 MB

    hipLaunchKernelGGL(gemm_partial, dim3((T_TOK / BM) * KSPLIT), dim3(256), 0, stream,
                       x, w, part);
    hipLaunchKernelGGL(topk_scatter, dim3(T_TOK / 4), dim3(256), 0, stream,
                       part, mm, bias, vbias, out);
}